// Round 15
// baseline (513.950 us; speedup 1.0000x reference)
//
#include <hip/hip_runtime.h>
#include <hip/hip_bf16.h>

#define HEADS 4
#define CH 64
#define HC 256

typedef __attribute__((ext_vector_type(8))) short short8;
typedef __attribute__((ext_vector_type(4))) float f32x4;
typedef __attribute__((ext_vector_type(8))) _Float16 half8;

typedef __attribute__((address_space(1))) const unsigned int as1_uint;
typedef __attribute__((address_space(3))) unsigned int as3_uint;

__device__ __forceinline__ void gll16(const void* g, void* l){
  __builtin_amdgcn_global_load_lds((as1_uint*)g, (as3_uint*)l, 16, 0, 0);
}

__device__ inline unsigned short f2bf(float f){
  unsigned u = __float_as_uint(f);
  return (unsigned short)((u + 0x7FFF + ((u >> 16) & 1)) >> 16);
}

// ---------------- CSR build ----------------

__global__ void hist_kernel(const int* __restrict__ dst, int E, int ET, int* __restrict__ cnt){
  int e = blockIdx.x * blockDim.x + threadIdx.x;
  if (e >= ET) return;
  int d = (e < E) ? dst[e] : (e - E);   // self-loop edges appended
  atomicAdd(&cnt[d], 1);
}

__global__ void blocksum_kernel(const int* __restrict__ cnt, int N, int* __restrict__ bsum){
  int tid = threadIdx.x;
  int i = blockIdx.x * 256 + tid;
  int v = (i < N) ? cnt[i] : 0;
  #pragma unroll
  for (int off = 32; off >= 1; off >>= 1) v += __shfl_xor(v, off);
  __shared__ int ws[4];
  if ((tid & 63) == 0) ws[tid >> 6] = v;
  __syncthreads();
  if (tid == 0) bsum[blockIdx.x] = ws[0] + ws[1] + ws[2] + ws[3];
}

__global__ void scanb_kernel(int* __restrict__ bsum, int nb){
  __shared__ int buf[256];
  int tid = threadIdx.x;
  int v = (tid < nb) ? bsum[tid] : 0;
  buf[tid] = v;
  __syncthreads();
  #pragma unroll
  for (int off = 1; off < 256; off <<= 1){
    int t = (tid >= off) ? buf[tid - off] : 0;
    __syncthreads();
    buf[tid] += t;
    __syncthreads();
  }
  if (tid < nb) bsum[tid] = buf[tid] - v;  // exclusive
}

__global__ void scanfinal_kernel(const int* __restrict__ cnt, const int* __restrict__ bsum,
                                 int* __restrict__ ptr, int* __restrict__ cur, int N){
  __shared__ int buf[256];
  int tid = threadIdx.x;
  int i = blockIdx.x * 256 + tid;
  int v = (i < N) ? cnt[i] : 0;
  buf[tid] = v;
  __syncthreads();
  #pragma unroll
  for (int off = 1; off < 256; off <<= 1){
    int t = (tid >= off) ? buf[tid - off] : 0;
    __syncthreads();
    buf[tid] += t;
    __syncthreads();
  }
  int exc = buf[tid] - v + bsum[blockIdx.x];
  if (i < N){
    ptr[i] = exc; cur[i] = exc;
    if (i == N - 1) ptr[N] = exc + v;
  }
}

__global__ void scatter_kernel(const int* __restrict__ src, const int* __restrict__ dst,
                               int E, int ET, int* __restrict__ cur,
                               int* __restrict__ csr_src){
  int e = blockIdx.x * blockDim.x + threadIdx.x;
  if (e >= ET) return;
  int s, d;
  if (e < E){ s = src[e]; d = dst[e]; } else { s = e - E; d = e - E; }
  int pos = atomicAdd(&cur[d], 1);
  csr_src[pos] = s;
}

// ---------------- degree counting-sort (LDS-staged histograms) ----------------

__global__ void dhist_kernel(const int* __restrict__ cnt, int N, int* __restrict__ dbins){
  __shared__ int lb[64];
  int tid = threadIdx.x;
  if (tid < 64) lb[tid] = 0;
  __syncthreads();
  int n = blockIdx.x * 256 + tid;
  if (n < N) atomicAdd(&lb[min(cnt[n], 63)], 1);
  __syncthreads();
  if (tid < 64 && lb[tid]) atomicAdd(&dbins[tid], lb[tid]);
}

__global__ void dscan_kernel(int* __restrict__ dbins, int* __restrict__ dcur){
  int lane = threadIdx.x;            // 64 threads = 1 wave
  int v = dbins[lane];
  int s = v;
  #pragma unroll
  for (int off = 1; off < 64; off <<= 1){
    int t = __shfl_up(s, off);
    if (lane >= off) s += t;
  }
  int exc = s - v;
  dbins[lane] = exc;
  dcur[lane] = exc;
}

__global__ void dscatter_kernel(const int* __restrict__ cnt, int N, int* __restrict__ dcur,
                                int* __restrict__ perm){
  __shared__ int lb[64];
  __shared__ int base[64];
  int tid = threadIdx.x;
  if (tid < 64) lb[tid] = 0;
  __syncthreads();
  int n = blockIdx.x * 256 + tid;
  bool valid = n < N;
  int bin = 0, rank = 0;
  if (valid){
    bin = min(cnt[n], 63);
    rank = atomicAdd(&lb[bin], 1);   // local rank within block's bin
  }
  __syncthreads();
  if (tid < 64) base[tid] = lb[tid] ? atomicAdd(&dcur[tid], lb[tid]) : 0;
  __syncthreads();
  if (valid) perm[base[bin] + rank] = n;
}

// ---------------- W convert: fp32 [K][256] -> fp16 transposed [256][K] (all 3 layers) ----------------

__global__ void wconv_kernel(const float* __restrict__ W0, _Float16* __restrict__ t0,
                             const float* __restrict__ W1, _Float16* __restrict__ t1,
                             const float* __restrict__ W2, _Float16* __restrict__ t2){
  int idx = blockIdx.x * 256 + threadIdx.x;
  const float* W; _Float16* T; int K;
  if (idx < 128 * HC){ W = W0; T = t0; K = 128; }
  else if (idx < (128 + 256) * HC){ idx -= 128 * HC; W = W1; T = t1; K = 256; }
  else { idx -= (128 + 256) * HC; W = W2; T = t2; K = 256; }
  int k = idx >> 8, n = idx & 255;
  T[(size_t)n * K + k] = (_Float16)W[idx];
}

// ---------------- x convert: fp32 -> fp16 ----------------

__global__ void xconv_kernel(const float* __restrict__ x, int total4, _Float16* __restrict__ xf){
  int i4 = blockIdx.x * 256 + threadIdx.x;
  if (i4 >= total4) return;
  float4 v = *(const float4*)&x[(size_t)i4 * 4];
  _Float16 o[4] = {(_Float16)v.x, (_Float16)v.y, (_Float16)v.z, (_Float16)v.w};
  *(ushort4*)&xf[(size_t)i4 * 4] = *(ushort4*)o;
}

// ---------------- head-weight pre-split (head keeps fp32-accurate bf16-split path) ----------------

__global__ void lwsplit_kernel(const float* __restrict__ lw0,
                               unsigned short* __restrict__ l0hi, unsigned short* __restrict__ l0lo,
                               const float* __restrict__ lw1, _Float16* __restrict__ l1T){
  int idx = blockIdx.x * 256 + threadIdx.x;
  if (idx < 8192){
    int n = idx & 127, k = idx >> 7;
    float w = lw0[k * 128 + n];
    unsigned short hb = f2bf(w);
    float hf = __uint_as_float((unsigned)hb << 16);
    unsigned short lb = f2bf(w - hf);
    l0hi[n * 64 + k] = hb;
    l0lo[n * 64 + k] = lb;
  } else if (idx < 8192 + 2048){
    int id = idx - 8192;
    int n = id & 15, k = id >> 4;
    float w = (n < 10) ? lw1[k * 10 + n] : 0.f;
    l1T[n * 128 + k] = (_Float16)w;
  }
}

// ---------------- fp16 MFMA GEMM, global_load_lds staging, LDS double-buffer ----------------

__launch_bounds__(256, 4)
__global__ void gemm_mfma_kernel(const _Float16* __restrict__ A,
                                 const _Float16* __restrict__ BT,
                                 _Float16* __restrict__ Cm,
                                 const float* __restrict__ att_s, const float* __restrict__ att_d,
                                 float* __restrict__ a_src, float* __restrict__ a_dst,
                                 int K){
  __shared__ __align__(16) unsigned short L[2][2][4096];

  int tid = threadIdx.x;
  int m0 = blockIdx.x * 128, n0 = blockIdx.y * 128;
  int wave = tid >> 6, lane = tid & 63;
  int wm = (wave >> 1) * 64, wn = (wave & 1) * 64;
  int col = lane & 15, quad = lane >> 4;

  f32x4 acc[4][4];
  #pragma unroll
  for (int a = 0; a < 4; a++)
    #pragma unroll
    for (int b = 0; b < 4; b++)
      acc[a][b] = (f32x4){0.f, 0.f, 0.f, 0.f};

  const int nIter = K >> 5;

  auto stage = [&](int buf, int kk){
    #pragma unroll
    for (int i = 0; i < 2; i++){
      int slotbase = (wave * 2 + i) * 64;          // wave-uniform
      int slot = slotbase + lane;
      int m = slot >> 2;
      int q = (lane & 3) ^ ((m >> 1) & 3);
      size_t ga = (size_t)(m0 + m) * K + kk + q * 8;
      size_t gb = (size_t)(n0 + m) * K + kk + q * 8;
      int lo = slotbase * 8;                        // shorts, wave-uniform
      gll16(&A[ga],  &L[buf][0][lo]);
      gll16(&BT[gb], &L[buf][1][lo]);
    }
  };

  stage(0, 0);

  for (int it = 0; it < nIter; it++){
    int buf = it & 1;
    __syncthreads();
    if (it + 1 < nIter) stage(buf ^ 1, (it + 1) << 5);

    half8 af[4], bf[4];
    #pragma unroll
    for (int t = 0; t < 4; t++){
      int rmA = wm + t * 16 + col;
      int rmB = wn + t * 16 + col;
      int sA = rmA * 4 + (quad ^ ((rmA >> 1) & 3));
      int sB = rmB * 4 + (quad ^ ((rmB >> 1) & 3));
      af[t] = *(const half8*)&L[buf][0][sA * 8];
      bf[t] = *(const half8*)&L[buf][1][sB * 8];
    }
    #pragma unroll
    for (int mt = 0; mt < 4; mt++)
      #pragma unroll
      for (int nt = 0; nt < 4; nt++)
        acc[mt][nt] = __builtin_amdgcn_mfma_f32_16x16x32_f16(af[mt], bf[nt], acc[mt][nt], 0, 0, 0);
  }

  // direct C store (fp16)
  #pragma unroll
  for (int mt = 0; mt < 4; mt++)
    #pragma unroll
    for (int nt = 0; nt < 4; nt++){
      int colg = n0 + wn + nt * 16 + col;
      #pragma unroll
      for (int r = 0; r < 4; r++){
        int row = m0 + wm + mt * 16 + quad * 4 + r;
        Cm[(size_t)row * HC + colg] = (_Float16)acc[mt][nt][r];
      }
    }

  // fused attention scores
  int head = (n0 + wn) >> 6;
  float asv[4], adv[4];
  #pragma unroll
  for (int nt = 0; nt < 4; nt++){
    asv[nt] = att_s[head * CH + nt * 16 + col];
    adv[nt] = att_d[head * CH + nt * 16 + col];
  }
  #pragma unroll
  for (int mt = 0; mt < 4; mt++){
    float sp[4] = {0.f,0.f,0.f,0.f}, dp[4] = {0.f,0.f,0.f,0.f};
    #pragma unroll
    for (int nt = 0; nt < 4; nt++)
      #pragma unroll
      for (int r = 0; r < 4; r++){
        sp[r] += acc[mt][nt][r] * asv[nt];
        dp[r] += acc[mt][nt][r] * adv[nt];
      }
    #pragma unroll
    for (int off = 1; off <= 8; off <<= 1)
      #pragma unroll
      for (int r = 0; r < 4; r++){
        sp[r] += __shfl_xor(sp[r], off);
        dp[r] += __shfl_xor(dp[r], off);
      }
    if (col == 0){
      #pragma unroll
      for (int r = 0; r < 4; r++){
        int row = m0 + wm + mt * 16 + quad * 4 + r;
        a_src[row * HEADS + head] = sp[r];
        a_dst[row * HEADS + head] = dp[r];
      }
    }
  }
}

// ---------------- softmax aggregation v5: LPT order + 8-wide batched loads ----------------
// block = 8 nodes (perm-ordered, processed largest-degree-first); wave = head;
// lane = slot(3b) x c8(3b). 8 edges' gathers issued before consuming.

__global__ void agg_kernel(const _Float16* __restrict__ h,
                           const float* __restrict__ a_src, const float* __restrict__ a_dst,
                           const int* __restrict__ ptr, const int* __restrict__ csr_src,
                           const int* __restrict__ perm,
                           const float* __restrict__ bias,
                           _Float16* __restrict__ outF,
                           int mean_mode, const float* __restrict__ b2,
                           float* __restrict__ f2){
  __shared__ float sm[HEADS][8][CH];
  int gb = gridDim.x - 1 - blockIdx.x;   // LPT: largest-degree blocks first
  int head = threadIdx.x >> 6;
  int lane = threadIdx.x & 63;
  int slot = lane >> 3, c8 = lane & 7;
  int pn = perm[gb * 8 + slot];
  int beg = 0, deg = 0;
  float adst = 0.f;
  if (pn >= 0){ beg = ptr[pn]; deg = ptr[pn + 1] - beg; adst = a_dst[pn * HEADS + head]; }

  int maxdeg = deg;
  #pragma unroll
  for (int off = 8; off <= 32; off <<= 1) maxdeg = max(maxdeg, __shfl_xor(maxdeg, off));

  float acc[8] = {0.f,0.f,0.f,0.f,0.f,0.f,0.f,0.f};
  float ss = 0.f;
  int it = 0;
  for (; it + 8 <= maxdeg; it += 8){
    int s[8];
    #pragma unroll
    for (int k = 0; k < 8; k++){
      int idx = beg + ((it + k < deg) ? it + k : 0);
      s[k] = csr_src[idx];
    }
    float as8[8];
    #pragma unroll
    for (int k = 0; k < 8; k++) as8[k] = a_src[s[k] * HEADS + head];
    half8 hv[8];
    #pragma unroll
    for (int k = 0; k < 8; k++)
      hv[k] = *(const half8*)&h[(size_t)s[k] * HC + head * CH + c8 * 8];
    float wv[8];
    #pragma unroll
    for (int k = 0; k < 8; k++){
      float e = as8[k] + adst;
      e = e > 0.f ? e : 0.2f * e;
      wv[k] = (it + k < deg) ? __expf(e) : 0.f;
    }
    #pragma unroll
    for (int k = 0; k < 8; k++){
      #pragma unroll
      for (int j = 0; j < 8; j++) acc[j] += wv[k] * (float)hv[k][j];
      ss += wv[k];
    }
  }
  for (; it < maxdeg; ++it){
    bool valid = it < deg;
    int idx = beg + (valid ? it : 0);
    int s = csr_src[idx];
    float e = a_src[s * HEADS + head] + adst;
    e = e > 0.f ? e : 0.2f * e;
    float wv = valid ? __expf(e) : 0.f;
    half8 hv = *(const half8*)&h[(size_t)s * HC + head * CH + c8 * 8];
    #pragma unroll
    for (int j = 0; j < 8; j++) acc[j] += wv * (float)hv[j];
    ss += wv;
  }
  float inv = 1.f / (ss + 1e-16f);
  #pragma unroll
  for (int j = 0; j < 8; j++) acc[j] *= inv;

  if (!mean_mode){
    if (pn >= 0){
      const float* bp = &bias[head * CH + c8 * 8];
      half8 o;
      #pragma unroll
      for (int j = 0; j < 8; j++) o[j] = (_Float16)(acc[j] + bp[j]);
      *(half8*)&outF[(size_t)pn * HC + head * CH + c8 * 8] = o;
    }
  } else {
    #pragma unroll
    for (int j = 0; j < 8; j++) sm[head][slot][c8 * 8 + j] = acc[j];
    __syncthreads();
    for (int t = threadIdx.x; t < 512; t += 256){
      int sl = t >> 6, ch = t & 63;
      int pn2 = perm[gb * 8 + sl];
      if (pn2 >= 0)
        f2[(size_t)pn2 * CH + ch] =
          0.25f * (sm[0][sl][ch] + sm[1][sl][ch] + sm[2][sl][ch] + sm[3][sl][ch]) + b2[ch];
    }
  }
}

// ---------------- fused MFMA MLP head (bf16-split, fp32-accurate) ----------------

__launch_bounds__(256, 2)
__global__ void head_mfma_kernel(const float* __restrict__ f2,
                                 const unsigned short* __restrict__ lw0hiT,
                                 const unsigned short* __restrict__ lw0loT,
                                 const _Float16* __restrict__ lw1T,
                                 const float* __restrict__ lb0,
                                 const float* __restrict__ lb1,
                                 float* __restrict__ outp, int N){
  __shared__ __align__(16) unsigned short L[27648];
  __shared__ __align__(16) _Float16 Ls[16][136];
  const int tid = threadIdx.x;
  const int wave = tid >> 6, lane = tid & 63;
  const int col = lane & 15, quad = lane >> 4;
  const int m0 = blockIdx.x * 64;

  { int n = tid >> 4, k = (tid & 15) * 8;
    *(half8*)&Ls[n][k] = *(const half8*)&lw1T[n * 128 + k]; }

  #pragma unroll
  for (int r = 0; r < 2; r++){
    int id = r * 256 + tid;
    int m = id >> 3, q = id & 7;
    int gm = m0 + m;
    float va[8];
    if (gm < N){
      float4 v0 = *(const float4*)&f2[(size_t)gm * CH + q * 8];
      float4 v1 = *(const float4*)&f2[(size_t)gm * CH + q * 8 + 4];
      va[0]=v0.x; va[1]=v0.y; va[2]=v0.z; va[3]=v0.w;
      va[4]=v1.x; va[5]=v1.y; va[6]=v1.z; va[7]=v1.w;
    } else {
      #pragma unroll
      for (int j = 0; j < 8; j++) va[j] = 0.f;
    }
    short8 hi8, lo8;
    #pragma unroll
    for (int j = 0; j < 8; j++){
      unsigned short hb = f2bf(va[j]);
      float hf = __uint_as_float((unsigned)hb << 16);
      hi8[j] = (short)hb;
      lo8[j] = (short)f2bf(va[j] - hf);
    }
    *(short8*)&L[m * 72 + q * 8] = hi8;
    *(short8*)&L[4608 + m * 72 + q * 8] = lo8;
  }
  #pragma unroll
  for (int r = 0; r < 4; r++){
    int id = r * 256 + tid;
    int n = id >> 3, q = id & 7;
    *(short8*)&L[9216 + n * 72 + q * 8]  = *(const short8*)&lw0hiT[n * 64 + q * 8];
    *(short8*)&L[18432 + n * 72 + q * 8] = *(const short8*)&lw0loT[n * 64 + q * 8];
  }
  __syncthreads();

  const int wn = wave * 32;
  f32x4 acc[4][2];
  #pragma unroll
  for (int a = 0; a < 4; a++)
    #pragma unroll
    for (int b = 0; b < 2; b++) acc[a][b] = (f32x4){0.f,0.f,0.f,0.f};

  #pragma unroll
  for (int ks = 0; ks < 2; ks++){
    int k = ks * 32 + quad * 8;
    short8 ah[4], al[4], bh[2], bl[2];
    #pragma unroll
    for (int mt = 0; mt < 4; mt++){
      ah[mt] = *(short8*)&L[(mt * 16 + col) * 72 + k];
      al[mt] = *(short8*)&L[4608 + (mt * 16 + col) * 72 + k];
    }
    #pragma unroll
    for (int nt = 0; nt < 2; nt++){
      bh[nt] = *(short8*)&L[9216 + (wn + nt * 16 + col) * 72 + k];
      bl[nt] = *(short8*)&L[18432 + (wn + nt * 16 + col) * 72 + k];
    }
    #pragma unroll
    for (int mt = 0; mt < 4; mt++)
      #pragma unroll
      for (int nt = 0; nt < 2; nt++){
        acc[mt][nt] = __builtin_amdgcn_mfma_f32_16x16x32_bf16(ah[mt], bh[nt], acc[mt][nt], 0, 0, 0);
        acc[mt][nt] = __builtin_amdgcn_mfma_f32_16x16x32_bf16(al[mt], bh[nt], acc[mt][nt], 0, 0, 0);
        acc[mt][nt] = __builtin_amdgcn_mfma_f32_16x16x32_bf16(ah[mt], bl[nt], acc[mt][nt], 0, 0, 0);
      }
  }
  __syncthreads();

  _Float16* Zp = (_Float16*)L;
  #pragma unroll
  for (int nt = 0; nt < 2; nt++){
    int n = wn + nt * 16 + col;
    float b = lb0[n];
    #pragma unroll
    for (int mt = 0; mt < 4; mt++)
      #pragma unroll
      for (int r2 = 0; r2 < 4; r2++){
        int m = mt * 16 + quad * 4 + r2;
        float z = acc[mt][nt][r2] + b;
        Zp[m * 136 + n] = (_Float16)fmaxf(z, 0.f);
      }
  }
  __syncthreads();

  f32x4 acc2 = (f32x4){0.f,0.f,0.f,0.f};
  #pragma unroll
  for (int ks = 0; ks < 4; ks++){
    int k = ks * 32 + quad * 8;
    half8 a2 = *(half8*)&Zp[(wave * 16 + col) * 136 + k];
    half8 b2v = *(half8*)&Ls[col][k];
    acc2 = __builtin_amdgcn_mfma_f32_16x16x32_f16(a2, b2v, acc2, 0, 0, 0);
  }
  if (col < 10){
    float bb = lb1[col];
    #pragma unroll
    for (int r2 = 0; r2 < 4; r2++){
      int row = m0 + wave * 16 + quad * 4 + r2;
      if (row < N) outp[(size_t)row * 10 + col] = acc2[r2] + bb;
    }
  }
}

// ---------------- launcher ----------------

extern "C" void kernel_launch(void* const* d_in, const int* in_sizes, int n_in,
                              void* d_out, int out_size, void* d_ws, size_t ws_size,
                              hipStream_t stream) {
  const float* x   = (const float*)d_in[0];
  const int*   ei  = (const int*)d_in[1];
  const float* W0  = (const float*)d_in[2];
  const float* as0 = (const float*)d_in[3];
  const float* ad0 = (const float*)d_in[4];
  const float* b0  = (const float*)d_in[5];
  const float* W1  = (const float*)d_in[6];
  const float* as1 = (const float*)d_in[7];
  const float* ad1 = (const float*)d_in[8];
  const float* b1  = (const float*)d_in[9];
  const float* W2  = (const float*)d_in[10];
  const float* as2 = (const float*)d_in[11];
  const float* ad2 = (const float*)d_in[12];
  const float* b2  = (const float*)d_in[13];
  const float* lw0 = (const float*)d_in[14];
  const float* lb0 = (const float*)d_in[15];
  const float* lw1 = (const float*)d_in[16];
  const float* lb1 = (const float*)d_in[17];
  float* outp = (float*)d_out;

  int N  = in_sizes[0] / 128;
  int E  = in_sizes[1] / 2;
  int ET = E + N;
  int nb = (N + 255) / 256;
  int Mp = ((N + 127) / 128) * 128;
  int Np8 = ((N + 7) / 8) * 8;

  char* ws = (char*)d_ws;
  _Float16* Hb  = (_Float16*)ws; ws += (size_t)Mp * HC * sizeof(_Float16);   // GEMM out / agg in
  _Float16* F   = (_Float16*)ws; ws += (size_t)Mp * HC * sizeof(_Float16);   // agg out / GEMM A
  _Float16* xf  = (_Float16*)ws; ws += (size_t)Mp * 128 * sizeof(_Float16);  // layer-0 A
  float* f2  = (float*)ws; ws += (size_t)N * CH * sizeof(float);
  float* a_s = (float*)ws; ws += (size_t)Mp * HEADS * sizeof(float);
  float* a_d = (float*)ws; ws += (size_t)Mp * HEADS * sizeof(float);
  int* cnt   = (int*)ws;   ws += (size_t)N * sizeof(int);
  int* cur   = (int*)ws;   ws += (size_t)N * sizeof(int);
  int* ptrA  = (int*)ws;   ws += (size_t)(N + 1) * sizeof(int);
  int* bsum  = (int*)ws;   ws += (size_t)nb * sizeof(int);
  int* csr   = (int*)ws;   ws += (size_t)ET * sizeof(int);
  int* perm  = (int*)ws;   ws += (size_t)Np8 * sizeof(int);
  int* dbins = (int*)ws;   ws += 64 * sizeof(int);
  int* dcur  = (int*)ws;   ws += 64 * sizeof(int);
  _Float16* w0T = (_Float16*)ws; ws += (size_t)128 * HC * sizeof(_Float16);
  _Float16* w1T = (_Float16*)ws; ws += (size_t)HC * HC * sizeof(_Float16);
  _Float16* w2T = (_Float16*)ws; ws += (size_t)HC * HC * sizeof(_Float16);
  unsigned short* l0hi = (unsigned short*)ws; ws += (size_t)8192 * 2;
  unsigned short* l0lo = (unsigned short*)ws; ws += (size_t)8192 * 2;
  _Float16* l1T        = (_Float16*)ws;       ws += (size_t)2048 * 2;

  const int* srcArr = ei;
  const int* dstArr = ei + E;

  // CSR build
  hipMemsetAsync(cnt, 0, (size_t)N * sizeof(int), stream);
  hipMemsetAsync(dbins, 0, 64 * sizeof(int), stream);
  hipMemsetAsync(perm, 0xFF, (size_t)Np8 * sizeof(int), stream);
  hist_kernel<<<(ET + 255) / 256, 256, 0, stream>>>(dstArr, E, ET, cnt);
  blocksum_kernel<<<nb, 256, 0, stream>>>(cnt, N, bsum);
  scanb_kernel<<<1, 256, 0, stream>>>(bsum, nb);
  scanfinal_kernel<<<nb, 256, 0, stream>>>(cnt, bsum, ptrA, cur, N);
  scatter_kernel<<<(ET + 255) / 256, 256, 0, stream>>>(srcArr, dstArr, E, ET, cur, csr);

  // degree sort (perm): nodes grouped by degree for uniform wave batches
  dhist_kernel<<<nb, 256, 0, stream>>>(cnt, N, dbins);
  dscan_kernel<<<1, 64, 0, stream>>>(dbins, dcur);
  dscatter_kernel<<<nb, 256, 0, stream>>>(cnt, N, dcur, perm);

  // weight converts + x convert
  wconv_kernel<<<((128 + 256 + 256) * HC) / 256, 256, 0, stream>>>(W0, w0T, W1, w1T, W2, w2T);
  lwsplit_kernel<<<(8192 + 2048 + 255) / 256, 256, 0, stream>>>(lw0, l0hi, l0lo, lw1, l1T);
  xconv_kernel<<<(N * 128 / 4 + 255) / 256, 256, 0, stream>>>(x, N * 128 / 4, xf);

  dim3 ggrid(Mp / 128, 2);
  int ab = Np8 / 8;

  // layer 0
  gemm_mfma_kernel<<<ggrid, 256, 0, stream>>>(xf, w0T, Hb, as0, ad0, a_s, a_d, 128);
  agg_kernel<<<ab, 256, 0, stream>>>(Hb, a_s, a_d, ptrA, csr, perm, b0, F, 0, nullptr, nullptr);

  // layer 1
  gemm_mfma_kernel<<<ggrid, 256, 0, stream>>>(F, w1T, Hb, as1, ad1, a_s, a_d, HC);
  agg_kernel<<<ab, 256, 0, stream>>>(Hb, a_s, a_d, ptrA, csr, perm, b1, F, 0, nullptr, nullptr);

  // layer 2 (mean over heads -> f2 fp32)
  gemm_mfma_kernel<<<ggrid, 256, 0, stream>>>(F, w2T, Hb, as2, ad2, a_s, a_d, HC);
  agg_kernel<<<ab, 256, 0, stream>>>(Hb, a_s, a_d, ptrA, csr, perm, nullptr, nullptr, 1, b2, f2);

  // MFMA MLP head
  head_mfma_kernel<<<(N + 63) / 64, 256, 0, stream>>>(f2, l0hi, l0lo, l1T, lb0, lb1, outp, N);
}

// Round 16
// 509.597 us; speedup vs baseline: 1.0085x; 1.0085x over previous
//
#include <hip/hip_runtime.h>
#include <hip/hip_bf16.h>

#define HEADS 4
#define CH 64
#define HC 256

typedef __attribute__((ext_vector_type(8))) short short8;
typedef __attribute__((ext_vector_type(4))) float f32x4;
typedef __attribute__((ext_vector_type(8))) _Float16 half8;

typedef __attribute__((address_space(1))) const unsigned int as1_uint;
typedef __attribute__((address_space(3))) unsigned int as3_uint;

__device__ __forceinline__ void gll16(const void* g, void* l){
  __builtin_amdgcn_global_load_lds((as1_uint*)g, (as3_uint*)l, 16, 0, 0);
}

__device__ inline unsigned short f2bf(float f){
  unsigned u = __float_as_uint(f);
  return (unsigned short)((u + 0x7FFF + ((u >> 16) & 1)) >> 16);
}

// ---------------- CSR build ----------------

__global__ void hist_kernel(const int* __restrict__ dst, int E, int ET, int* __restrict__ cnt){
  int e = blockIdx.x * blockDim.x + threadIdx.x;
  if (e >= ET) return;
  int d = (e < E) ? dst[e] : (e - E);   // self-loop edges appended
  atomicAdd(&cnt[d], 1);
}

__global__ void blocksum_kernel(const int* __restrict__ cnt, int N, int* __restrict__ bsum){
  int tid = threadIdx.x;
  int i = blockIdx.x * 256 + tid;
  int v = (i < N) ? cnt[i] : 0;
  #pragma unroll
  for (int off = 32; off >= 1; off >>= 1) v += __shfl_xor(v, off);
  __shared__ int ws[4];
  if ((tid & 63) == 0) ws[tid >> 6] = v;
  __syncthreads();
  if (tid == 0) bsum[blockIdx.x] = ws[0] + ws[1] + ws[2] + ws[3];
}

__global__ void scanb_kernel(int* __restrict__ bsum, int nb){
  __shared__ int buf[256];
  int tid = threadIdx.x;
  int v = (tid < nb) ? bsum[tid] : 0;
  buf[tid] = v;
  __syncthreads();
  #pragma unroll
  for (int off = 1; off < 256; off <<= 1){
    int t = (tid >= off) ? buf[tid - off] : 0;
    __syncthreads();
    buf[tid] += t;
    __syncthreads();
  }
  if (tid < nb) bsum[tid] = buf[tid] - v;  // exclusive
}

__global__ void scanfinal_kernel(const int* __restrict__ cnt, const int* __restrict__ bsum,
                                 int* __restrict__ ptr, int* __restrict__ cur, int N){
  __shared__ int buf[256];
  int tid = threadIdx.x;
  int i = blockIdx.x * 256 + tid;
  int v = (i < N) ? cnt[i] : 0;
  buf[tid] = v;
  __syncthreads();
  #pragma unroll
  for (int off = 1; off < 256; off <<= 1){
    int t = (tid >= off) ? buf[tid - off] : 0;
    __syncthreads();
    buf[tid] += t;
    __syncthreads();
  }
  int exc = buf[tid] - v + bsum[blockIdx.x];
  if (i < N){
    ptr[i] = exc; cur[i] = exc;
    if (i == N - 1) ptr[N] = exc + v;
  }
}

__global__ void scatter_kernel(const int* __restrict__ src, const int* __restrict__ dst,
                               int E, int ET, int* __restrict__ cur,
                               int* __restrict__ csr_src){
  int e = blockIdx.x * blockDim.x + threadIdx.x;
  if (e >= ET) return;
  int s, d;
  if (e < E){ s = src[e]; d = dst[e]; } else { s = e - E; d = e - E; }
  int pos = atomicAdd(&cur[d], 1);
  csr_src[pos] = s;
}

// ---------------- degree counting-sort (LDS-staged histograms) ----------------

__global__ void dhist_kernel(const int* __restrict__ cnt, int N, int* __restrict__ dbins){
  __shared__ int lb[64];
  int tid = threadIdx.x;
  if (tid < 64) lb[tid] = 0;
  __syncthreads();
  int n = blockIdx.x * 256 + tid;
  if (n < N) atomicAdd(&lb[min(cnt[n], 63)], 1);
  __syncthreads();
  if (tid < 64 && lb[tid]) atomicAdd(&dbins[tid], lb[tid]);
}

__global__ void dscan_kernel(int* __restrict__ dbins, int* __restrict__ dcur){
  int lane = threadIdx.x;            // 64 threads = 1 wave
  int v = dbins[lane];
  int s = v;
  #pragma unroll
  for (int off = 1; off < 64; off <<= 1){
    int t = __shfl_up(s, off);
    if (lane >= off) s += t;
  }
  int exc = s - v;
  dbins[lane] = exc;
  dcur[lane] = exc;
}

__global__ void dscatter_kernel(const int* __restrict__ cnt, int N, int* __restrict__ dcur,
                                int* __restrict__ perm){
  __shared__ int lb[64];
  __shared__ int base[64];
  int tid = threadIdx.x;
  if (tid < 64) lb[tid] = 0;
  __syncthreads();
  int n = blockIdx.x * 256 + tid;
  bool valid = n < N;
  int bin = 0, rank = 0;
  if (valid){
    bin = min(cnt[n], 63);
    rank = atomicAdd(&lb[bin], 1);   // local rank within block's bin
  }
  __syncthreads();
  if (tid < 64) base[tid] = lb[tid] ? atomicAdd(&dcur[tid], lb[tid]) : 0;
  __syncthreads();
  if (valid) perm[base[bin] + rank] = n;
}

// ---------------- W convert: fp32 [K][256] -> fp16 transposed [256][K] (all 3 layers) ----------------

__global__ void wconv_kernel(const float* __restrict__ W0, _Float16* __restrict__ t0,
                             const float* __restrict__ W1, _Float16* __restrict__ t1,
                             const float* __restrict__ W2, _Float16* __restrict__ t2){
  int idx = blockIdx.x * 256 + threadIdx.x;
  const float* W; _Float16* T; int K;
  if (idx < 128 * HC){ W = W0; T = t0; K = 128; }
  else if (idx < (128 + 256) * HC){ idx -= 128 * HC; W = W1; T = t1; K = 256; }
  else { idx -= (128 + 256) * HC; W = W2; T = t2; K = 256; }
  int k = idx >> 8, n = idx & 255;
  T[(size_t)n * K + k] = (_Float16)W[idx];
}

// ---------------- x convert: fp32 -> fp16 ----------------

__global__ void xconv_kernel(const float* __restrict__ x, int total4, _Float16* __restrict__ xf){
  int i4 = blockIdx.x * 256 + threadIdx.x;
  if (i4 >= total4) return;
  float4 v = *(const float4*)&x[(size_t)i4 * 4];
  _Float16 o[4] = {(_Float16)v.x, (_Float16)v.y, (_Float16)v.z, (_Float16)v.w};
  *(ushort4*)&xf[(size_t)i4 * 4] = *(ushort4*)o;
}

// ---------------- head-weight pre-split (head keeps fp32-accurate bf16-split path) ----------------

__global__ void lwsplit_kernel(const float* __restrict__ lw0,
                               unsigned short* __restrict__ l0hi, unsigned short* __restrict__ l0lo,
                               const float* __restrict__ lw1, _Float16* __restrict__ l1T){
  int idx = blockIdx.x * 256 + threadIdx.x;
  if (idx < 8192){
    int n = idx & 127, k = idx >> 7;
    float w = lw0[k * 128 + n];
    unsigned short hb = f2bf(w);
    float hf = __uint_as_float((unsigned)hb << 16);
    unsigned short lb = f2bf(w - hf);
    l0hi[n * 64 + k] = hb;
    l0lo[n * 64 + k] = lb;
  } else if (idx < 8192 + 2048){
    int id = idx - 8192;
    int n = id & 15, k = id >> 4;
    float w = (n < 10) ? lw1[k * 10 + n] : 0.f;
    l1T[n * 128 + k] = (_Float16)w;
  }
}

// ---------------- fp16 MFMA GEMM, global_load_lds staging, LDS double-buffer ----------------

__launch_bounds__(256, 4)
__global__ void gemm_mfma_kernel(const _Float16* __restrict__ A,
                                 const _Float16* __restrict__ BT,
                                 _Float16* __restrict__ Cm,
                                 const float* __restrict__ att_s, const float* __restrict__ att_d,
                                 float* __restrict__ a_src, float* __restrict__ a_dst,
                                 int K){
  __shared__ __align__(16) unsigned short L[2][2][4096];

  int tid = threadIdx.x;
  int m0 = blockIdx.x * 128, n0 = blockIdx.y * 128;
  int wave = tid >> 6, lane = tid & 63;
  int wm = (wave >> 1) * 64, wn = (wave & 1) * 64;
  int col = lane & 15, quad = lane >> 4;

  f32x4 acc[4][4];
  #pragma unroll
  for (int a = 0; a < 4; a++)
    #pragma unroll
    for (int b = 0; b < 4; b++)
      acc[a][b] = (f32x4){0.f, 0.f, 0.f, 0.f};

  const int nIter = K >> 5;

  auto stage = [&](int buf, int kk){
    #pragma unroll
    for (int i = 0; i < 2; i++){
      int slotbase = (wave * 2 + i) * 64;          // wave-uniform
      int slot = slotbase + lane;
      int m = slot >> 2;
      int q = (lane & 3) ^ ((m >> 1) & 3);
      size_t ga = (size_t)(m0 + m) * K + kk + q * 8;
      size_t gb = (size_t)(n0 + m) * K + kk + q * 8;
      int lo = slotbase * 8;                        // shorts, wave-uniform
      gll16(&A[ga],  &L[buf][0][lo]);
      gll16(&BT[gb], &L[buf][1][lo]);
    }
  };

  stage(0, 0);

  for (int it = 0; it < nIter; it++){
    int buf = it & 1;
    __syncthreads();
    if (it + 1 < nIter) stage(buf ^ 1, (it + 1) << 5);

    half8 af[4], bf[4];
    #pragma unroll
    for (int t = 0; t < 4; t++){
      int rmA = wm + t * 16 + col;
      int rmB = wn + t * 16 + col;
      int sA = rmA * 4 + (quad ^ ((rmA >> 1) & 3));
      int sB = rmB * 4 + (quad ^ ((rmB >> 1) & 3));
      af[t] = *(const half8*)&L[buf][0][sA * 8];
      bf[t] = *(const half8*)&L[buf][1][sB * 8];
    }
    #pragma unroll
    for (int mt = 0; mt < 4; mt++)
      #pragma unroll
      for (int nt = 0; nt < 4; nt++)
        acc[mt][nt] = __builtin_amdgcn_mfma_f32_16x16x32_f16(af[mt], bf[nt], acc[mt][nt], 0, 0, 0);
  }

  // direct C store (fp16)
  #pragma unroll
  for (int mt = 0; mt < 4; mt++)
    #pragma unroll
    for (int nt = 0; nt < 4; nt++){
      int colg = n0 + wn + nt * 16 + col;
      #pragma unroll
      for (int r = 0; r < 4; r++){
        int row = m0 + wm + mt * 16 + quad * 4 + r;
        Cm[(size_t)row * HC + colg] = (_Float16)acc[mt][nt][r];
      }
    }

  // fused attention scores
  int head = (n0 + wn) >> 6;
  float asv[4], adv[4];
  #pragma unroll
  for (int nt = 0; nt < 4; nt++){
    asv[nt] = att_s[head * CH + nt * 16 + col];
    adv[nt] = att_d[head * CH + nt * 16 + col];
  }
  #pragma unroll
  for (int mt = 0; mt < 4; mt++){
    float sp[4] = {0.f,0.f,0.f,0.f}, dp[4] = {0.f,0.f,0.f,0.f};
    #pragma unroll
    for (int nt = 0; nt < 4; nt++)
      #pragma unroll
      for (int r = 0; r < 4; r++){
        sp[r] += acc[mt][nt][r] * asv[nt];
        dp[r] += acc[mt][nt][r] * adv[nt];
      }
    #pragma unroll
    for (int off = 1; off <= 8; off <<= 1)
      #pragma unroll
      for (int r = 0; r < 4; r++){
        sp[r] += __shfl_xor(sp[r], off);
        dp[r] += __shfl_xor(dp[r], off);
      }
    if (col == 0){
      #pragma unroll
      for (int r = 0; r < 4; r++){
        int row = m0 + wm + mt * 16 + quad * 4 + r;
        a_src[row * HEADS + head] = sp[r];
        a_dst[row * HEADS + head] = dp[r];
      }
    }
  }
}

// ---------------- softmax aggregation (R13 config: 4-wide batch, natural order) ----------------
// block = 8 nodes (perm-ordered); wave = head; lane = slot(3b) x c8(3b).

__global__ void agg_kernel(const _Float16* __restrict__ h,
                           const float* __restrict__ a_src, const float* __restrict__ a_dst,
                           const int* __restrict__ ptr, const int* __restrict__ csr_src,
                           const int* __restrict__ perm,
                           const float* __restrict__ bias,
                           _Float16* __restrict__ outF,
                           int mean_mode, const float* __restrict__ b2,
                           float* __restrict__ f2){
  __shared__ float sm[HEADS][8][CH];
  int head = threadIdx.x >> 6;
  int lane = threadIdx.x & 63;
  int slot = lane >> 3, c8 = lane & 7;
  int pn = perm[blockIdx.x * 8 + slot];
  int beg = 0, deg = 0;
  float adst = 0.f;
  if (pn >= 0){ beg = ptr[pn]; deg = ptr[pn + 1] - beg; adst = a_dst[pn * HEADS + head]; }

  int maxdeg = deg;
  #pragma unroll
  for (int off = 8; off <= 32; off <<= 1) maxdeg = max(maxdeg, __shfl_xor(maxdeg, off));

  float acc[8] = {0.f,0.f,0.f,0.f,0.f,0.f,0.f,0.f};
  float ss = 0.f;
  int it = 0;
  for (; it + 4 <= maxdeg; it += 4){
    int s[4]; float as4[4];
    #pragma unroll
    for (int k = 0; k < 4; k++){
      int idx = beg + ((it + k < deg) ? it + k : 0);
      s[k] = csr_src[idx];
    }
    #pragma unroll
    for (int k = 0; k < 4; k++) as4[k] = a_src[s[k] * HEADS + head];
    half8 h0 = *(const half8*)&h[(size_t)s[0] * HC + head * CH + c8 * 8];
    half8 h1 = *(const half8*)&h[(size_t)s[1] * HC + head * CH + c8 * 8];
    half8 h2 = *(const half8*)&h[(size_t)s[2] * HC + head * CH + c8 * 8];
    half8 h3 = *(const half8*)&h[(size_t)s[3] * HC + head * CH + c8 * 8];
    float wv[4];
    #pragma unroll
    for (int k = 0; k < 4; k++){
      float e = as4[k] + adst;
      e = e > 0.f ? e : 0.2f * e;
      wv[k] = (it + k < deg) ? __expf(e) : 0.f;
    }
    #pragma unroll
    for (int j = 0; j < 8; j++){
      acc[j] += wv[0] * (float)h0[j];
      acc[j] += wv[1] * (float)h1[j];
      acc[j] += wv[2] * (float)h2[j];
      acc[j] += wv[3] * (float)h3[j];
    }
    ss += wv[0] + wv[1] + wv[2] + wv[3];
  }
  for (; it < maxdeg; ++it){
    bool valid = it < deg;
    int idx = beg + (valid ? it : 0);
    int s = csr_src[idx];
    float e = a_src[s * HEADS + head] + adst;
    e = e > 0.f ? e : 0.2f * e;
    float wv = valid ? __expf(e) : 0.f;
    half8 hv = *(const half8*)&h[(size_t)s * HC + head * CH + c8 * 8];
    #pragma unroll
    for (int j = 0; j < 8; j++) acc[j] += wv * (float)hv[j];
    ss += wv;
  }
  float inv = 1.f / (ss + 1e-16f);
  #pragma unroll
  for (int j = 0; j < 8; j++) acc[j] *= inv;

  if (!mean_mode){
    if (pn >= 0){
      const float* bp = &bias[head * CH + c8 * 8];
      half8 o;
      #pragma unroll
      for (int j = 0; j < 8; j++) o[j] = (_Float16)(acc[j] + bp[j]);
      *(half8*)&outF[(size_t)pn * HC + head * CH + c8 * 8] = o;
    }
  } else {
    #pragma unroll
    for (int j = 0; j < 8; j++) sm[head][slot][c8 * 8 + j] = acc[j];
    __syncthreads();
    for (int t = threadIdx.x; t < 512; t += 256){
      int sl = t >> 6, ch = t & 63;
      int pn2 = perm[blockIdx.x * 8 + sl];
      if (pn2 >= 0)
        f2[(size_t)pn2 * CH + ch] =
          0.25f * (sm[0][sl][ch] + sm[1][sl][ch] + sm[2][sl][ch] + sm[3][sl][ch]) + b2[ch];
    }
  }
}

// ---------------- fused MFMA MLP head (bf16-split, fp32-accurate) ----------------

__launch_bounds__(256, 2)
__global__ void head_mfma_kernel(const float* __restrict__ f2,
                                 const unsigned short* __restrict__ lw0hiT,
                                 const unsigned short* __restrict__ lw0loT,
                                 const _Float16* __restrict__ lw1T,
                                 const float* __restrict__ lb0,
                                 const float* __restrict__ lb1,
                                 float* __restrict__ outp, int N){
  __shared__ __align__(16) unsigned short L[27648];
  __shared__ __align__(16) _Float16 Ls[16][136];
  const int tid = threadIdx.x;
  const int wave = tid >> 6, lane = tid & 63;
  const int col = lane & 15, quad = lane >> 4;
  const int m0 = blockIdx.x * 64;

  { int n = tid >> 4, k = (tid & 15) * 8;
    *(half8*)&Ls[n][k] = *(const half8*)&lw1T[n * 128 + k]; }

  #pragma unroll
  for (int r = 0; r < 2; r++){
    int id = r * 256 + tid;
    int m = id >> 3, q = id & 7;
    int gm = m0 + m;
    float va[8];
    if (gm < N){
      float4 v0 = *(const float4*)&f2[(size_t)gm * CH + q * 8];
      float4 v1 = *(const float4*)&f2[(size_t)gm * CH + q * 8 + 4];
      va[0]=v0.x; va[1]=v0.y; va[2]=v0.z; va[3]=v0.w;
      va[4]=v1.x; va[5]=v1.y; va[6]=v1.z; va[7]=v1.w;
    } else {
      #pragma unroll
      for (int j = 0; j < 8; j++) va[j] = 0.f;
    }
    short8 hi8, lo8;
    #pragma unroll
    for (int j = 0; j < 8; j++){
      unsigned short hb = f2bf(va[j]);
      float hf = __uint_as_float((unsigned)hb << 16);
      hi8[j] = (short)hb;
      lo8[j] = (short)f2bf(va[j] - hf);
    }
    *(short8*)&L[m * 72 + q * 8] = hi8;
    *(short8*)&L[4608 + m * 72 + q * 8] = lo8;
  }
  #pragma unroll
  for (int r = 0; r < 4; r++){
    int id = r * 256 + tid;
    int n = id >> 3, q = id & 7;
    *(short8*)&L[9216 + n * 72 + q * 8]  = *(const short8*)&lw0hiT[n * 64 + q * 8];
    *(short8*)&L[18432 + n * 72 + q * 8] = *(const short8*)&lw0loT[n * 64 + q * 8];
  }
  __syncthreads();

  const int wn = wave * 32;
  f32x4 acc[4][2];
  #pragma unroll
  for (int a = 0; a < 4; a++)
    #pragma unroll
    for (int b = 0; b < 2; b++) acc[a][b] = (f32x4){0.f,0.f,0.f,0.f};

  #pragma unroll
  for (int ks = 0; ks < 2; ks++){
    int k = ks * 32 + quad * 8;
    short8 ah[4], al[4], bh[2], bl[2];
    #pragma unroll
    for (int mt = 0; mt < 4; mt++){
      ah[mt] = *(short8*)&L[(mt * 16 + col) * 72 + k];
      al[mt] = *(short8*)&L[4608 + (mt * 16 + col) * 72 + k];
    }
    #pragma unroll
    for (int nt = 0; nt < 2; nt++){
      bh[nt] = *(short8*)&L[9216 + (wn + nt * 16 + col) * 72 + k];
      bl[nt] = *(short8*)&L[18432 + (wn + nt * 16 + col) * 72 + k];
    }
    #pragma unroll
    for (int mt = 0; mt < 4; mt++)
      #pragma unroll
      for (int nt = 0; nt < 2; nt++){
        acc[mt][nt] = __builtin_amdgcn_mfma_f32_16x16x32_bf16(ah[mt], bh[nt], acc[mt][nt], 0, 0, 0);
        acc[mt][nt] = __builtin_amdgcn_mfma_f32_16x16x32_bf16(al[mt], bh[nt], acc[mt][nt], 0, 0, 0);
        acc[mt][nt] = __builtin_amdgcn_mfma_f32_16x16x32_bf16(ah[mt], bl[nt], acc[mt][nt], 0, 0, 0);
      }
  }
  __syncthreads();

  _Float16* Zp = (_Float16*)L;
  #pragma unroll
  for (int nt = 0; nt < 2; nt++){
    int n = wn + nt * 16 + col;
    float b = lb0[n];
    #pragma unroll
    for (int mt = 0; mt < 4; mt++)
      #pragma unroll
      for (int r2 = 0; r2 < 4; r2++){
        int m = mt * 16 + quad * 4 + r2;
        float z = acc[mt][nt][r2] + b;
        Zp[m * 136 + n] = (_Float16)fmaxf(z, 0.f);
      }
  }
  __syncthreads();

  f32x4 acc2 = (f32x4){0.f,0.f,0.f,0.f};
  #pragma unroll
  for (int ks = 0; ks < 4; ks++){
    int k = ks * 32 + quad * 8;
    half8 a2 = *(half8*)&Zp[(wave * 16 + col) * 136 + k];
    half8 b2v = *(half8*)&Ls[col][k];
    acc2 = __builtin_amdgcn_mfma_f32_16x16x32_f16(a2, b2v, acc2, 0, 0, 0);
  }
  if (col < 10){
    float bb = lb1[col];
    #pragma unroll
    for (int r2 = 0; r2 < 4; r2++){
      int row = m0 + wave * 16 + quad * 4 + r2;
      if (row < N) outp[(size_t)row * 10 + col] = acc2[r2] + bb;
    }
  }
}

// ---------------- launcher ----------------

extern "C" void kernel_launch(void* const* d_in, const int* in_sizes, int n_in,
                              void* d_out, int out_size, void* d_ws, size_t ws_size,
                              hipStream_t stream) {
  const float* x   = (const float*)d_in[0];
  const int*   ei  = (const int*)d_in[1];
  const float* W0  = (const float*)d_in[2];
  const float* as0 = (const float*)d_in[3];
  const float* ad0 = (const float*)d_in[4];
  const float* b0  = (const float*)d_in[5];
  const float* W1  = (const float*)d_in[6];
  const float* as1 = (const float*)d_in[7];
  const float* ad1 = (const float*)d_in[8];
  const float* b1  = (const float*)d_in[9];
  const float* W2  = (const float*)d_in[10];
  const float* as2 = (const float*)d_in[11];
  const float* ad2 = (const float*)d_in[12];
  const float* b2  = (const float*)d_in[13];
  const float* lw0 = (const float*)d_in[14];
  const float* lb0 = (const float*)d_in[15];
  const float* lw1 = (const float*)d_in[16];
  const float* lb1 = (const float*)d_in[17];
  float* outp = (float*)d_out;

  int N  = in_sizes[0] / 128;
  int E  = in_sizes[1] / 2;
  int ET = E + N;
  int nb = (N + 255) / 256;
  int Mp = ((N + 127) / 128) * 128;
  int Np8 = ((N + 7) / 8) * 8;

  char* ws = (char*)d_ws;
  _Float16* Hb  = (_Float16*)ws; ws += (size_t)Mp * HC * sizeof(_Float16);   // GEMM out / agg in
  _Float16* F   = (_Float16*)ws; ws += (size_t)Mp * HC * sizeof(_Float16);   // agg out / GEMM A
  _Float16* xf  = (_Float16*)ws; ws += (size_t)Mp * 128 * sizeof(_Float16);  // layer-0 A
  float* f2  = (float*)ws; ws += (size_t)N * CH * sizeof(float);
  float* a_s = (float*)ws; ws += (size_t)Mp * HEADS * sizeof(float);
  float* a_d = (float*)ws; ws += (size_t)Mp * HEADS * sizeof(float);
  int* cnt   = (int*)ws;   ws += (size_t)N * sizeof(int);
  int* cur   = (int*)ws;   ws += (size_t)N * sizeof(int);
  int* ptrA  = (int*)ws;   ws += (size_t)(N + 1) * sizeof(int);
  int* bsum  = (int*)ws;   ws += (size_t)nb * sizeof(int);
  int* csr   = (int*)ws;   ws += (size_t)ET * sizeof(int);
  int* perm  = (int*)ws;   ws += (size_t)Np8 * sizeof(int);
  int* dbins = (int*)ws;   ws += 64 * sizeof(int);
  int* dcur  = (int*)ws;   ws += 64 * sizeof(int);
  _Float16* w0T = (_Float16*)ws; ws += (size_t)128 * HC * sizeof(_Float16);
  _Float16* w1T = (_Float16*)ws; ws += (size_t)HC * HC * sizeof(_Float16);
  _Float16* w2T = (_Float16*)ws; ws += (size_t)HC * HC * sizeof(_Float16);
  unsigned short* l0hi = (unsigned short*)ws; ws += (size_t)8192 * 2;
  unsigned short* l0lo = (unsigned short*)ws; ws += (size_t)8192 * 2;
  _Float16* l1T        = (_Float16*)ws;       ws += (size_t)2048 * 2;

  const int* srcArr = ei;
  const int* dstArr = ei + E;

  // CSR build
  hipMemsetAsync(cnt, 0, (size_t)N * sizeof(int), stream);
  hipMemsetAsync(dbins, 0, 64 * sizeof(int), stream);
  hipMemsetAsync(perm, 0xFF, (size_t)Np8 * sizeof(int), stream);
  hist_kernel<<<(ET + 255) / 256, 256, 0, stream>>>(dstArr, E, ET, cnt);
  blocksum_kernel<<<nb, 256, 0, stream>>>(cnt, N, bsum);
  scanb_kernel<<<1, 256, 0, stream>>>(bsum, nb);
  scanfinal_kernel<<<nb, 256, 0, stream>>>(cnt, bsum, ptrA, cur, N);
  scatter_kernel<<<(ET + 255) / 256, 256, 0, stream>>>(srcArr, dstArr, E, ET, cur, csr);

  // degree sort (perm): nodes grouped by degree for uniform wave batches
  dhist_kernel<<<nb, 256, 0, stream>>>(cnt, N, dbins);
  dscan_kernel<<<1, 64, 0, stream>>>(dbins, dcur);
  dscatter_kernel<<<nb, 256, 0, stream>>>(cnt, N, dcur, perm);

  // weight converts + x convert
  wconv_kernel<<<((128 + 256 + 256) * HC) / 256, 256, 0, stream>>>(W0, w0T, W1, w1T, W2, w2T);
  lwsplit_kernel<<<(8192 + 2048 + 255) / 256, 256, 0, stream>>>(lw0, l0hi, l0lo, lw1, l1T);
  xconv_kernel<<<(N * 128 / 4 + 255) / 256, 256, 0, stream>>>(x, N * 128 / 4, xf);

  dim3 ggrid(Mp / 128, 2);
  int ab = Np8 / 8;

  // layer 0
  gemm_mfma_kernel<<<ggrid, 256, 0, stream>>>(xf, w0T, Hb, as0, ad0, a_s, a_d, 128);
  agg_kernel<<<ab, 256, 0, stream>>>(Hb, a_s, a_d, ptrA, csr, perm, b0, F, 0, nullptr, nullptr);

  // layer 1
  gemm_mfma_kernel<<<ggrid, 256, 0, stream>>>(F, w1T, Hb, as1, ad1, a_s, a_d, HC);
  agg_kernel<<<ab, 256, 0, stream>>>(Hb, a_s, a_d, ptrA, csr, perm, b1, F, 0, nullptr, nullptr);

  // layer 2 (mean over heads -> f2 fp32)
  gemm_mfma_kernel<<<ggrid, 256, 0, stream>>>(F, w2T, Hb, as2, ad2, a_s, a_d, HC);
  agg_kernel<<<ab, 256, 0, stream>>>(Hb, a_s, a_d, ptrA, csr, perm, nullptr, nullptr, 1, b2, f2);

  // MFMA MLP head
  head_mfma_kernel<<<(N + 63) / 64, 256, 0, stream>>>(f2, l0hi, l0lo, l1T, lb0, lb1, outp, N);
}